// Round 9
// baseline (1350.537 us; speedup 1.0000x reference)
//
#include <hip/hip_runtime.h>

#define DEV __device__ __forceinline__

typedef __attribute__((ext_vector_type(8))) short short8;
typedef __bf16 bf16x8 __attribute__((ext_vector_type(8)));
typedef __attribute__((ext_vector_type(4))) float f32x4;
typedef __attribute__((ext_vector_type(2))) unsigned uint2v;
typedef __attribute__((ext_vector_type(4))) unsigned uint4v;

constexpr int NB = 16;
constexpr int NN = 64;
constexpr int ND = 512;
constexpr int NH = 8;

DEV float b2f(unsigned short h) { return __uint_as_float(((unsigned)h) << 16); }
DEV unsigned short f2b(float f) {
    unsigned u = __float_as_uint(f);
    return (unsigned short)((u + 0x7fffu + ((u >> 16) & 1u)) >> 16);
}
// mish(x) = x*(t^2+2t)/(t^2+2t+2), t=e^x; x>15 -> x
DEV float mish_fast(float x) {
    float t = __expf(x);
    float w = t * (t + 2.0f);
    float r = x * w * __builtin_amdgcn_rcpf(w + 2.0f);
    return (x > 15.0f) ? x : r;
}
DEV void gload16(const unsigned short* g, unsigned short* lds) {
    __builtin_amdgcn_global_load_lds((const __attribute__((address_space(1))) void*)g,
                                     (__attribute__((address_space(3))) void*)lds,
                                     16, 0, 0);
}

#define WAITV(N) asm volatile("s_waitcnt vmcnt(" #N ")" ::: "memory")
#define WAITL()  asm volatile("s_waitcnt lgkmcnt(0)" ::: "memory")

// ---------------------------------------------------------------------------
__global__ __launch_bounds__(64)
void probe_dtype(const unsigned* __restrict__ adj, int* __restrict__ flag)
{
    int t = threadIdx.x;
    int c = 0;
#pragma unroll
    for (int i = 0; i < 4; ++i) c += (int)((adj[t * 4 + i] >> 15) & 1u);
    for (int off = 32; off; off >>= 1) c += __shfl_xor(c, off);
    if (t == 0) flag[0] = (c > 32) ? 1 : 0;
}

// ---------------------------------------------------------------------------
__global__ __launch_bounds__(256)
void wtrans(const void* W0, const void* W1, const void* W2, const void* W3,
            const void* W4, unsigned short* __restrict__ out,
            const int* __restrict__ flag)
{
    const void* W = (blockIdx.z == 0) ? W0 : (blockIdx.z == 1) ? W1 :
                    (blockIdx.z == 2) ? W2 : (blockIdx.z == 3) ? W3 : W4;
    const int f32 = flag[0];
    unsigned short* o = out + (size_t)blockIdx.z * 262144;
    __shared__ unsigned short tile[64][65];
    const int t = threadIdx.x;
    const int k0 = blockIdx.x * 64, c0 = blockIdx.y * 64;
#pragma unroll
    for (int rep = 0; rep < 16; ++rep) {
        int idx = rep * 256 + t;
        int r = idx >> 6, c = idx & 63;
        size_t gi = (size_t)(k0 + r) * 512 + c0 + c;
        float v = f32 ? ((const float*)W)[gi]
                      : b2f(((const unsigned short*)W)[gi]);
        tile[r][c] = f2b(v);
    }
    __syncthreads();
#pragma unroll
    for (int rep = 0; rep < 16; ++rep) {
        int idx = rep * 256 + t;
        int cc = idx >> 6, kk = idx & 63;
        o[(size_t)(c0 + cc) * 512 + k0 + kk] = tile[kk][cc];
    }
}

// ---------------------------------------------------------------------------
// GEMM v6: out[128 x 512 per block] = f( A[128 x 512] @ W + bias )
// 512 thr / 8 waves (2M x 4N), wave tile 64x128 (4x8 frags, 128 acc VGPR).
// 80 KB LDS -> 2 blocks/CU (4 waves/SIMD): latency hidden by cross-block
// TLP (m97/m114 mechanism), not in-block pipeline depth.
// Per step: issue A(s+1)(regs)+B(s+1)(gload_lds, ping-pong) at top; 12 frag
// ds_reads + lgkmcnt(0) + 64 MFMA; WAITV(4) -> writeA; lgkmcnt(0)+vmcnt(0)
// -> one barrier.
// LDS layouts (bank-audited, exactly 8 dwords/bank per wave64 b128 op):
//   Ab[2][128][32]sh: granule g of row r at slot g^((r>>1)&3)
//   Bb[2][512][32]sh: k-granule p of col c at slot p^((c>>1)&3)
// AMODE: 0 = raw input (f32 per flag / bf16), 1 = bf16, 2 = bf16 * msg.
// In-place safe: all A reads precede epilogue writes; blocks own disjoint
// 128-row ranges.
// ---------------------------------------------------------------------------
template<int AMODE, bool MISH, bool OUTF32>
__global__ __launch_bounds__(512, 4)
void gemm6(const void* A, long long apitch,
           const unsigned short* __restrict__ Bt,
           const void* __restrict__ bias_raw,
           const float* __restrict__ msg,
           void* out, long long opitch,
           const int* __restrict__ flag,
           const void* A2, const unsigned short* Bt2,
           const void* bias2, void* out2)
{
    __shared__ alignas(16) unsigned short Ab[2][128][32];   // 16 KB
    __shared__ alignas(16) unsigned short Bb[2][512][32];   // 64 KB
    const int f32g = flag[0];
    const int t = threadIdx.x;
    const int lane = t & 63;
    const int wv = t >> 6;
    const int wm = wv >> 2;          // 0..1
    const int wn = wv & 3;           // 0..3

    long long row0;
    const void* Ap = A; const unsigned short* Btp = Bt;
    const void* biasp = bias_raw; void* outp = out;
    if (A2 != nullptr && (int)blockIdx.x >= (int)(gridDim.x >> 1)) {
        Ap = A2; Btp = Bt2; biasp = bias2; outp = out2;
        row0 = (long long)(blockIdx.x - (gridDim.x >> 1)) * 128;
    } else {
        row0 = (long long)blockIdx.x * 128;
    }

    const int rA = lane & 15;
    const int p  = lane >> 4;                       // k-granule 0..3
    const int sl = (p ^ ((rA >> 1) & 3)) * 8;       // frag-read slot (shorts)
    // A staging: thread t -> row 0..127, granule 0..3
    const int arow = t >> 2;
    const int ag   = t & 3;
    const long long grA = row0 + arow;
    const int aslot_sh = (ag ^ ((t >> 3) & 3)) * 8;
    // B staging lane constants
    const int bcf = lane >> 2;                      // col fine 0..15
    const int bg  = (lane & 3) ^ ((lane >> 3) & 3); // pre-swizzled src granule

    const float* mptr = nullptr;
    if (AMODE == 2) {
        int b = (int)(grA >> 12), m = (int)(grA >> 6) & 63, n = (int)grA & 63;
        mptr = msg + (((long long)b * 8) * 64 + m) * 64 + n;   // + (x>>1)*4096
    }

    f32x4 acc[4][8];
#pragma unroll
    for (int mi = 0; mi < 4; ++mi)
#pragma unroll
        for (int ni = 0; ni < 8; ++ni) acc[mi][ni] = f32x4{0.f, 0.f, 0.f, 0.f};

    // ---- staging helpers (x = K-step 0..15); single reg slot (depth-1) ----
    uint4v rf0, rf1;     // AMODE0 f32 path
    uint2v rh0, rh1;     // AMODE0 bf16 path
    short8 rs;           // AMODE1/2
    float  msv;
    auto loadA = [&](int x) {
        if (AMODE == 0) {
            if (f32g) {
                const float* src = (const float*)Ap + grA * apitch + x * 32 + ag * 8;
                rf0 = *reinterpret_cast<const uint4v*>(src);
                rf1 = *reinterpret_cast<const uint4v*>(src + 4);
            } else {
                const unsigned short* src = (const unsigned short*)Ap + grA * apitch + x * 32 + ag * 8;
                rh0 = *reinterpret_cast<const uint2v*>(src);
                rh1 = *reinterpret_cast<const uint2v*>(src + 4);
            }
        } else {
            rs = *reinterpret_cast<const short8*>(
                (const unsigned short*)Ap + grA * apitch + x * 32 + ag * 8);
            if (AMODE == 2) msv = mptr[(x >> 1) * 4096];
        }
    };
    auto writeA = [&](int x) {
        unsigned short h[8];
        if (AMODE == 0) {
            if (f32g) {
#pragma unroll
                for (int j = 0; j < 4; ++j) {
                    h[j]     = f2b(__uint_as_float(rf0[j]));
                    h[j + 4] = f2b(__uint_as_float(rf1[j]));
                }
            } else {
#pragma unroll
                for (int j = 0; j < 2; ++j) {
                    h[j * 2]         = (unsigned short)(rh0[j] & 0xffff);
                    h[j * 2 + 1]     = (unsigned short)(rh0[j] >> 16);
                    h[4 + j * 2]     = (unsigned short)(rh1[j] & 0xffff);
                    h[4 + j * 2 + 1] = (unsigned short)(rh1[j] >> 16);
                }
            }
        } else {
#pragma unroll
            for (int j = 0; j < 8; ++j) h[j] = (unsigned short)rs[j];
            if (AMODE == 2) {
#pragma unroll
                for (int j = 0; j < 8; ++j) h[j] = f2b(b2f(h[j]) * msv);
            }
        }
        short8 sv;
#pragma unroll
        for (int j = 0; j < 8; ++j) sv[j] = (short)h[j];
        *reinterpret_cast<short8*>(&Ab[x & 1][arow][aslot_sh]) = sv;
    };
    auto issueB = [&](int x) {
#pragma unroll
        for (int j = 0; j < 4; ++j) {
            int colb = wv * 64 + j * 16;
            const unsigned short* src =
                Btp + (size_t)(colb + bcf) * 512 + x * 32 + bg * 8;
            gload16(src, &Bb[x & 1][colb][0]);
        }
    };

    // ---- prologue: stage step 0 ----
    loadA(0); issueB(0);
    WAITV(4);            // drain A(0) regs (leave B(0)'s 4 in flight)
    writeA(0);
    WAITL(); WAITV(0);   // A ds_writes + B gloads done
    __builtin_amdgcn_s_barrier();

    // ---- 16 K-steps, ping-pong, 1 barrier + 1 full drain per step ----
#pragma unroll
    for (int s = 0; s < 16; ++s) {
        if (s < 15) { loadA(s + 1); issueB(s + 1); }

        bf16x8 af[4], bf[8];
#pragma unroll
        for (int mi = 0; mi < 4; ++mi)
            af[mi] = *reinterpret_cast<const bf16x8*>(
                &Ab[s & 1][wm * 64 + mi * 16 + rA][sl]);
#pragma unroll
        for (int ni = 0; ni < 8; ++ni)
            bf[ni] = *reinterpret_cast<const bf16x8*>(
                &Bb[s & 1][wn * 128 + ni * 16 + rA][sl]);
        WAITL();
        __builtin_amdgcn_sched_barrier(0);
        __builtin_amdgcn_s_setprio(1);
#pragma unroll
        for (int mi = 0; mi < 4; ++mi)
#pragma unroll
            for (int ni = 0; ni < 8; ++ni)
                acc[mi][ni] = __builtin_amdgcn_mfma_f32_16x16x32_bf16(
                    af[mi], bf[ni], acc[mi][ni], 0, 0, 0);
        __builtin_amdgcn_s_setprio(0);

        if (s < 15) {
            WAITV(4);            // drain A(s+1) regs
            writeA(s + 1);
            WAITL(); WAITV(0);   // publish A ds_writes; B(s+1) landed
            __builtin_amdgcn_s_barrier();
        }
    }

    // ---- epilogue: C/D layout col=lane&15, row=(lane>>4)*4+rr ----
    const int orow_q = (lane >> 4) * 4;
#pragma unroll
    for (int mi = 0; mi < 4; ++mi) {
#pragma unroll
        for (int ni = 0; ni < 8; ++ni) {
            int col = wn * 128 + ni * 16 + rA;
            float bz = f32g ? ((const float*)biasp)[col]
                            : b2f(((const unsigned short*)biasp)[col]);
            long long rbase = row0 + wm * 64 + mi * 16 + orow_q;
#pragma unroll
            for (int rr = 0; rr < 4; ++rr) {
                float v = acc[mi][ni][rr] + bz;
                if (MISH) v = mish_fast(v);
                long long oi = (rbase + rr) * opitch + col;
                if (OUTF32) ((float*)outp)[oi] = v;
                else        ((unsigned short*)outp)[oi] = f2b(v);
            }
        }
    }
}

// ---------------------------------------------------------------------------
// Pass A: raw scores, kp read EXACTLY ONCE (verified rounds 6-8).
// ---------------------------------------------------------------------------
__global__ __launch_bounds__(256)
void score_kernel(const unsigned short* __restrict__ q,
                  const unsigned short* __restrict__ kp,
                  float* __restrict__ outS,
                  float* __restrict__ inS)
{
    const int bid = blockIdx.x;            // 512 blocks
    const int b  = bid >> 5;
    const int i0 = ((bid >> 2) & 7) * 8;
    const int j0 = (bid & 3) * 16;
    const int t = threadIdx.x, lane = t & 63, wv = t >> 6;

    __shared__ alignas(16) unsigned short qs[24][512];
    __shared__ float souts[8][16][8];
    __shared__ float sins[16][8][8];

#pragma unroll
    for (int r8 = 0; r8 < 6; ++r8) {
        int r = wv * 6 + r8;
        int grow = (r < 8) ? (i0 + r) : (j0 + r - 8);
        gload16(q + ((long long)(b * 64 + grow)) * 512 + lane * 8, &qs[r][0]);
    }
    __syncthreads();

    for (int batch = 0; batch < 4; ++batch) {
        const int rbase = wv * 32 + batch * 8;
        short8 kv[8];
#pragma unroll
        for (int u = 0; u < 8; ++u) {
            int r = rbase + u;
            int ii = r >> 4, jj = r & 15;
            kv[u] = *reinterpret_cast<const short8*>(
                kp + ((long long)((b * 64 + i0 + ii) * 64) + j0 + jj) * 1024 + lane * 8);
        }
#pragma unroll
        for (int u = 0; u < 8; ++u) {
            int r = rbase + u;
            int ii = r >> 4, jj = r & 15;
            short8 qi = *reinterpret_cast<const short8*>(&qs[ii][lane * 8]);
            short8 qj = *reinterpret_cast<const short8*>(&qs[8 + jj][lane * 8]);
            float so = 0.f, si = 0.f;
#pragma unroll
            for (int e = 0; e < 8; ++e) {
                float kf = b2f((unsigned short)kv[u][e]);
                so += kf * b2f((unsigned short)qi[e]);
                si += kf * b2f((unsigned short)qj[e]);
            }
#pragma unroll
            for (int off = 1; off < 8; off <<= 1) {
                so += __shfl_xor(so, off);
                si += __shfl_xor(si, off);
            }
            if ((lane & 7) == 0) {
                souts[ii][jj][lane >> 3] = so * 0.125f;
                sins[jj][ii][lane >> 3]  = si * 0.125f;
            }
        }
    }
    __syncthreads();

    {
        int h  = t >> 5;
        int ii = (t >> 2) & 7;
        int qq = t & 3;
        f32x4 v;
#pragma unroll
        for (int e = 0; e < 4; ++e) v[e] = souts[ii][qq * 4 + e][h];
        *reinterpret_cast<f32x4*>(
            &outS[(((long long)(b * 8 + h) * 64) + i0 + ii) * 64 + j0 + qq * 4]) = v;
    }
    {
        int h  = t >> 5;
        int jj = (t >> 1) & 15;
        int hf = t & 1;
        f32x4 v;
#pragma unroll
        for (int e = 0; e < 4; ++e) v[e] = sins[jj][hf * 4 + e][h];
        *reinterpret_cast<f32x4*>(
            &inS[(((long long)(b * 8 + h) * 64) + j0 + jj) * 64 + i0 + hf * 4]) = v;
    }
}

// ---------------------------------------------------------------------------
__global__ __launch_bounds__(256)
void softmax_combine(float* __restrict__ outS, const float* __restrict__ inS)
{
    const long long row = (long long)blockIdx.x * 4 + (threadIdx.x >> 6);
    const int l = threadIdx.x & 63;
    const int x = (int)(row & 63);
    float so = outS[row * 64 + l];
    float si = inS[row * 64 + l];
    float mo = so, mi = si;
    for (int off = 32; off; off >>= 1) {
        mo = fmaxf(mo, __shfl_xor(mo, off));
        mi = fmaxf(mi, __shfl_xor(mi, off));
    }
    float eo = __expf(so - mo), ei = __expf(si - mi);
    float zo = eo, zi = ei;
    for (int off = 32; off; off >>= 1) {
        zo += __shfl_xor(zo, off);
        zi += __shfl_xor(zi, off);
    }
    float ao = eo / zo, ai = ei / zi;
    outS[row * 64 + l] = (l == x) ? ai : (ao + ai);
}

// ---------------------------------------------------------------------------
__global__ __launch_bounds__(512)
void nh_kernel(const float* __restrict__ msg,
               const unsigned short* __restrict__ v,
               unsigned short* __restrict__ nh)
{
    const int bm = blockIdx.x;
    const int b = bm >> 6, m = bm & 63;
    const int t = threadIdx.x;
    __shared__ float ms2[8 * 64];
    ms2[t] = msg[((long long)b * 8 + (t >> 6)) * 4096 + m * 64 + (t & 63)];
    __syncthreads();
    const float* mrow = &ms2[(t >> 6) * 64];
    float acc = 0.f;
#pragma unroll 8
    for (int n = 0; n < 64; ++n)
        acc += mrow[n] * b2f(v[((long long)b * 64 + n) * 512 + t]);
    nh[(long long)bm * 1024 + t] = f2b(acc);
}

// ---------------------------------------------------------------------------
extern "C" void kernel_launch(void* const* d_in, const int* in_sizes, int n_in,
                              void* d_out, int out_size, void* d_ws, size_t ws_size,
                              hipStream_t stream)
{
    const void* qn = d_in[0];
    const void* vn = d_in[1];
    const void* ke = d_in[2];
    const unsigned* adj = (const unsigned*)d_in[3];
    const void* Wq = d_in[4];  const void* bq = d_in[5];
    const void* Wk = d_in[6];  const void* bk = d_in[7];
    const void* Wv = d_in[8];  const void* bv = d_in[9];
    const void* Wn = d_in[10]; const void* bn = d_in[11];
    const void* We = d_in[12]; const void* be = d_in[13];

    float* out_node = (float*)d_out;                       // 16*64*512 f32 (2 MB)
    float* out_edge = out_node + (size_t)NB * NN * ND;     // 16*64*64*512 f32
    unsigned short* kp = (unsigned short*)out_edge;        // bf16, pitch 1024 shorts
    unsigned short* nh = (unsigned short*)out_node;        // bf16, pitch 1024 shorts
    float* inS = out_node;  // in-scores scratch (2 MB) — dead before nh_kernel

    char* wsb = (char*)d_ws;
    int* flag = (int*)wsb;
    unsigned short* Wt  = (unsigned short*)(wsb + 16);     // 5 x 512 KB
    unsigned short* Wqt = Wt + 0 * 262144;
    unsigned short* Wkt = Wt + 1 * 262144;
    unsigned short* Wvt = Wt + 2 * 262144;
    unsigned short* Wnt = Wt + 3 * 262144;
    unsigned short* Wet = Wt + 4 * 262144;
    unsigned short* q_ws = Wt + 5 * 262144;                // 1 MB bf16
    unsigned short* v_ws = q_ws + 524288;                  // 1 MB bf16
    float* msg = (float*)(v_ws + 524288);                  // 2 MB f32
    // ws total ~6.5 MB

    probe_dtype<<<1, 64, 0, stream>>>(adj, flag);
    wtrans<<<dim3(8, 8, 5), 256, 0, stream>>>(Wq, Wk, Wv, Wn, We, Wt, flag);
    // q + v projections merged (f32 A): blocks 0-7 -> q, 8-15 -> v
    gemm6<0, false, false><<<16, 512, 0, stream>>>(
        qn, 512, Wqt, bq, nullptr, q_ws, 512, flag, vn, Wvt, bv, v_ws);
    // k projection -> strided bf16 inside the edge f32 output region
    gemm6<0, false, false><<<512, 512, 0, stream>>>(
        ke, 512, Wkt, bk, nullptr, kp, 1024, flag, nullptr, nullptr, nullptr, nullptr);
    // message: raw scores (kp read once) + softmax/combine
    score_kernel<<<512, 256, 0, stream>>>(q_ws, kp, msg, inS);
    softmax_combine<<<2048, 256, 0, stream>>>(msg, inS);
    // node path
    nh_kernel<<<NB * NN, 512, 0, stream>>>(msg, v_ws, nh);
    gemm6<1, true, true><<<8, 512, 0, stream>>>(
        nh, 1024, Wnt, bn, nullptr, out_node, 512, flag, nullptr, nullptr, nullptr, nullptr);
    // edge path: msg-scaling fused into A-staging; in-place
    gemm6<2, true, true><<<512, 512, 0, stream>>>(
        kp, 1024, Wet, be, msg, out_edge, 512, flag, nullptr, nullptr, nullptr, nullptr);
}

// Round 10
// 281.339 us; speedup vs baseline: 4.8004x; 4.8004x over previous
//
#include <hip/hip_runtime.h>

#define DEV __device__ __forceinline__

typedef __attribute__((ext_vector_type(8))) short short8;
typedef __bf16 bf16x8 __attribute__((ext_vector_type(8)));
typedef __attribute__((ext_vector_type(4))) float f32x4;
typedef __attribute__((ext_vector_type(2))) unsigned uint2v;
typedef __attribute__((ext_vector_type(4))) unsigned uint4v;

constexpr int NB = 16;
constexpr int NN = 64;
constexpr int ND = 512;
constexpr int NH = 8;

DEV float b2f(unsigned short h) { return __uint_as_float(((unsigned)h) << 16); }
DEV unsigned short f2b(float f) {
    unsigned u = __float_as_uint(f);
    return (unsigned short)((u + 0x7fffu + ((u >> 16) & 1u)) >> 16);
}
// mish(x) = x*(t^2+2t)/(t^2+2t+2), t=e^x; x>15 -> x
DEV float mish_fast(float x) {
    float t = __expf(x);
    float w = t * (t + 2.0f);
    float r = x * w * __builtin_amdgcn_rcpf(w + 2.0f);
    return (x > 15.0f) ? x : r;
}
DEV void gload16(const unsigned short* g, unsigned short* lds) {
    __builtin_amdgcn_global_load_lds((const __attribute__((address_space(1))) void*)g,
                                     (__attribute__((address_space(3))) void*)lds,
                                     16, 0, 0);
}

#define WAITV(N) asm volatile("s_waitcnt vmcnt(" #N ")" ::: "memory")
#define WAITL()  asm volatile("s_waitcnt lgkmcnt(0)" ::: "memory")

// ---------------------------------------------------------------------------
__global__ __launch_bounds__(64)
void probe_dtype(const unsigned* __restrict__ adj, int* __restrict__ flag)
{
    int t = threadIdx.x;
    int c = 0;
#pragma unroll
    for (int i = 0; i < 4; ++i) c += (int)((adj[t * 4 + i] >> 15) & 1u);
    for (int off = 32; off; off >>= 1) c += __shfl_xor(c, off);
    if (t == 0) flag[0] = (c > 32) ? 1 : 0;
}

// ---------------------------------------------------------------------------
__global__ __launch_bounds__(256)
void wtrans(const void* W0, const void* W1, const void* W2, const void* W3,
            const void* W4, unsigned short* __restrict__ out,
            const int* __restrict__ flag)
{
    const void* W = (blockIdx.z == 0) ? W0 : (blockIdx.z == 1) ? W1 :
                    (blockIdx.z == 2) ? W2 : (blockIdx.z == 3) ? W3 : W4;
    const int f32 = flag[0];
    unsigned short* o = out + (size_t)blockIdx.z * 262144;
    __shared__ unsigned short tile[64][65];
    const int t = threadIdx.x;
    const int k0 = blockIdx.x * 64, c0 = blockIdx.y * 64;
#pragma unroll
    for (int rep = 0; rep < 16; ++rep) {
        int idx = rep * 256 + t;
        int r = idx >> 6, c = idx & 63;
        size_t gi = (size_t)(k0 + r) * 512 + c0 + c;
        float v = f32 ? ((const float*)W)[gi]
                      : b2f(((const unsigned short*)W)[gi]);
        tile[r][c] = f2b(v);
    }
    __syncthreads();
#pragma unroll
    for (int rep = 0; rep < 16; ++rep) {
        int idx = rep * 256 + t;
        int cc = idx >> 6, kk = idx & 63;
        o[(size_t)(c0 + cc) * 512 + k0 + kk] = tile[kk][cc];
    }
}

// ---------------------------------------------------------------------------
// GEMM v7: out[64 x 512 per block] = f( A[64 x 512] @ W + bias )
// 256 thr / 4 waves; wave tile 64x128 (4x8 frags, acc = 128 VGPR; total ~200
// -> NO spill at 2 waves/SIMD; launch_bounds(256,2)).
// 72 KB LDS -> 2 blocks/CU: two independent barrier domains per CU overlap
// each other's stalls (m114 mechanism) without cutting the VGPR budget
// (round-9's spill lesson).
// Per step s (in-order vmcnt derivation in comments):
//   WAITV(0)              A(s+1) regs landed (issued top of s-1, 1 step ago)
//   writeA(s+1)           ds_write -> Ab[(s+1)&1]
//   issueB(s+1)           8 gload16 -> Bb[(s+1)&1]
//   loadA(s+2)            L global loads -> regs
//   frag ds_reads + lgkmcnt(0) + 32 MFMA
//   lgkmcnt(0); WAITV(L)  B(s+1) landed (8 issued before A's L); A(s+2) flies
//   s_barrier
// LDS layouts (bank-audited, 8 dwords/bank per wave64 b128 op):
//   Ab[2][64][32]sh:  granule g of row r at slot g^((r>>1)&3)
//   Bb[2][512][32]sh: k-granule p of col c at slot p^((c>>1)&3)
// AMODE: 0 = raw input (f32 per flag / bf16), 1 = bf16, 2 = bf16 * msg.
// In-place safe: all A reads precede epilogue writes; blocks own disjoint
// 64-row ranges.
// ---------------------------------------------------------------------------
template<int AMODE, bool MISH, bool OUTF32>
__global__ __launch_bounds__(256, 2)
void gemm7(const void* A, long long apitch,
           const unsigned short* __restrict__ Bt,
           const void* __restrict__ bias_raw,
           const float* __restrict__ msg,
           void* out, long long opitch,
           const int* __restrict__ flag,
           const void* A2, const unsigned short* Bt2,
           const void* bias2, void* out2)
{
    constexpr int L = (AMODE == 1) ? 1 : 2;
    __shared__ alignas(16) unsigned short Ab[2][64][32];    //  8 KB
    __shared__ alignas(16) unsigned short Bb[2][512][32];   // 64 KB
    const int f32g = flag[0];
    const int t = threadIdx.x;
    const int lane = t & 63;
    const int wv = t >> 6;           // 0..3 = N-quadrant

    long long row0;
    const void* Ap = A; const unsigned short* Btp = Bt;
    const void* biasp = bias_raw; void* outp = out;
    if (A2 != nullptr && (int)blockIdx.x >= (int)(gridDim.x >> 1)) {
        Ap = A2; Btp = Bt2; biasp = bias2; outp = out2;
        row0 = (long long)(blockIdx.x - (gridDim.x >> 1)) * 64;
    } else {
        row0 = (long long)blockIdx.x * 64;
    }

    const int rA = lane & 15;
    const int p  = lane >> 4;                       // k-granule 0..3
    const int sl = (p ^ ((rA >> 1) & 3)) * 8;       // frag-read slot (shorts)
    // A staging: thread t -> row 0..63, granule 0..3
    const int arow = t >> 2;
    const int ag   = t & 3;
    const long long grA = row0 + arow;
    const int aslot_sh = (ag ^ ((arow >> 1) & 3)) * 8;
    // B staging lane constants
    const int bcf = lane >> 2;                      // col fine 0..15
    const int bg  = (lane & 3) ^ ((lane >> 3) & 3); // pre-swizzled src granule

    const float* mptr = nullptr;
    if (AMODE == 2) {
        int b = (int)(grA >> 12), m = (int)(grA >> 6) & 63, n = (int)grA & 63;
        mptr = msg + (((long long)b * 8) * 64 + m) * 64 + n;   // + (x>>1)*4096
    }

    f32x4 acc[4][8];
#pragma unroll
    for (int mi = 0; mi < 4; ++mi)
#pragma unroll
        for (int ni = 0; ni < 8; ++ni) acc[mi][ni] = f32x4{0.f, 0.f, 0.f, 0.f};

    // ---- staging helpers (x = K-step 0..15); single reg slot ----
    uint4v rf0, rf1;     // AMODE0 f32 path
    uint2v rh0, rh1;     // AMODE0 bf16 path
    short8 rs;           // AMODE1/2
    float  msv;
    auto loadA = [&](int x) {
        if (AMODE == 0) {
            if (f32g) {
                const float* src = (const float*)Ap + grA * apitch + x * 32 + ag * 8;
                rf0 = *reinterpret_cast<const uint4v*>(src);
                rf1 = *reinterpret_cast<const uint4v*>(src + 4);
            } else {
                const unsigned short* src = (const unsigned short*)Ap + grA * apitch + x * 32 + ag * 8;
                rh0 = *reinterpret_cast<const uint2v*>(src);
                rh1 = *reinterpret_cast<const uint2v*>(src + 4);
            }
        } else {
            rs = *reinterpret_cast<const short8*>(
                (const unsigned short*)Ap + grA * apitch + x * 32 + ag * 8);
            if (AMODE == 2) msv = mptr[(x >> 1) * 4096];
        }
    };
    auto writeA = [&](int x) {
        unsigned short h[8];
        if (AMODE == 0) {
            if (f32g) {
#pragma unroll
                for (int j = 0; j < 4; ++j) {
                    h[j]     = f2b(__uint_as_float(rf0[j]));
                    h[j + 4] = f2b(__uint_as_float(rf1[j]));
                }
            } else {
#pragma unroll
                for (int j = 0; j < 2; ++j) {
                    h[j * 2]         = (unsigned short)(rh0[j] & 0xffff);
                    h[j * 2 + 1]     = (unsigned short)(rh0[j] >> 16);
                    h[4 + j * 2]     = (unsigned short)(rh1[j] & 0xffff);
                    h[4 + j * 2 + 1] = (unsigned short)(rh1[j] >> 16);
                }
            }
        } else {
#pragma unroll
            for (int j = 0; j < 8; ++j) h[j] = (unsigned short)rs[j];
            if (AMODE == 2) {
#pragma unroll
                for (int j = 0; j < 8; ++j) h[j] = f2b(b2f(h[j]) * msv);
            }
        }
        short8 sv;
#pragma unroll
        for (int j = 0; j < 8; ++j) sv[j] = (short)h[j];
        *reinterpret_cast<short8*>(&Ab[x & 1][arow][aslot_sh]) = sv;
    };
    auto issueB = [&](int x) {
#pragma unroll
        for (int j = 0; j < 8; ++j) {
            int colb = wv * 128 + j * 16;
            const unsigned short* src =
                Btp + (size_t)(colb + bcf) * 512 + x * 32 + bg * 8;
            gload16(src, &Bb[x & 1][colb][0]);
        }
    };

    // ---- prologue ----
    loadA(0);
    WAITV(0);            // A(0) regs landed
    writeA(0);
    issueB(0);           // queue: [B0(8)]
    loadA(1);            // queue: [B0(8), A1(L)]
    WAITL();             // A(0) ds_write done
    if constexpr (L == 1) WAITV(1); else WAITV(2);   // B0 landed; A1 in flight
    __builtin_amdgcn_s_barrier();

    // ---- 16 K-steps, ping-pong ----
#pragma unroll
    for (int s = 0; s < 16; ++s) {
        if (s < 15) {
            WAITV(0);                 // A(s+1) regs landed (issued 1 step ago)
            writeA(s + 1);            // -> Ab[(s+1)&1]
            issueB(s + 1);            // -> Bb[(s+1)&1]
            if (s < 14) loadA(s + 2);
        }

        bf16x8 af[4], bf[8];
#pragma unroll
        for (int mi = 0; mi < 4; ++mi)
            af[mi] = *reinterpret_cast<const bf16x8*>(
                &Ab[s & 1][mi * 16 + rA][sl]);
#pragma unroll
        for (int ni = 0; ni < 8; ++ni)
            bf[ni] = *reinterpret_cast<const bf16x8*>(
                &Bb[s & 1][wv * 128 + ni * 16 + rA][sl]);
        WAITL();
        __builtin_amdgcn_sched_barrier(0);
        __builtin_amdgcn_s_setprio(1);
#pragma unroll
        for (int mi = 0; mi < 4; ++mi)
#pragma unroll
            for (int ni = 0; ni < 8; ++ni)
                acc[mi][ni] = __builtin_amdgcn_mfma_f32_16x16x32_bf16(
                    af[mi], bf[ni], acc[mi][ni], 0, 0, 0);
        __builtin_amdgcn_s_setprio(0);

        if (s < 15) {
            WAITL();                  // A(s+1) ds_write visible
            if (s < 14) {             // B(s+1) landed; A(s+2) stays in flight
                if constexpr (L == 1) WAITV(1); else WAITV(2);
            } else {
                WAITV(0);             // s==14: nothing issued after B(15)
            }
            __builtin_amdgcn_s_barrier();
        }
    }

    // ---- epilogue: C/D layout col=lane&15, row=(lane>>4)*4+rr ----
    const int orow_q = (lane >> 4) * 4;
#pragma unroll
    for (int mi = 0; mi < 4; ++mi) {
#pragma unroll
        for (int ni = 0; ni < 8; ++ni) {
            int col = wv * 128 + ni * 16 + rA;
            float bz = f32g ? ((const float*)biasp)[col]
                            : b2f(((const unsigned short*)biasp)[col]);
            long long rbase = row0 + mi * 16 + orow_q;
#pragma unroll
            for (int rr = 0; rr < 4; ++rr) {
                float v = acc[mi][ni][rr] + bz;
                if (MISH) v = mish_fast(v);
                long long oi = (rbase + rr) * opitch + col;
                if (OUTF32) ((float*)outp)[oi] = v;
                else        ((unsigned short*)outp)[oi] = f2b(v);
            }
        }
    }
}

// ---------------------------------------------------------------------------
// Pass A: raw scores, kp read EXACTLY ONCE (verified rounds 6-9).
// ---------------------------------------------------------------------------
__global__ __launch_bounds__(256)
void score_kernel(const unsigned short* __restrict__ q,
                  const unsigned short* __restrict__ kp,
                  float* __restrict__ outS,
                  float* __restrict__ inS)
{
    const int bid = blockIdx.x;            // 512 blocks
    const int b  = bid >> 5;
    const int i0 = ((bid >> 2) & 7) * 8;
    const int j0 = (bid & 3) * 16;
    const int t = threadIdx.x, lane = t & 63, wv = t >> 6;

    __shared__ alignas(16) unsigned short qs[24][512];
    __shared__ float souts[8][16][8];
    __shared__ float sins[16][8][8];

#pragma unroll
    for (int r8 = 0; r8 < 6; ++r8) {
        int r = wv * 6 + r8;
        int grow = (r < 8) ? (i0 + r) : (j0 + r - 8);
        gload16(q + ((long long)(b * 64 + grow)) * 512 + lane * 8, &qs[r][0]);
    }
    __syncthreads();

    for (int batch = 0; batch < 4; ++batch) {
        const int rbase = wv * 32 + batch * 8;
        short8 kv[8];
#pragma unroll
        for (int u = 0; u < 8; ++u) {
            int r = rbase + u;
            int ii = r >> 4, jj = r & 15;
            kv[u] = *reinterpret_cast<const short8*>(
                kp + ((long long)((b * 64 + i0 + ii) * 64) + j0 + jj) * 1024 + lane * 8);
        }
#pragma unroll
        for (int u = 0; u < 8; ++u) {
            int r = rbase + u;
            int ii = r >> 4, jj = r & 15;
            short8 qi = *reinterpret_cast<const short8*>(&qs[ii][lane * 8]);
            short8 qj = *reinterpret_cast<const short8*>(&qs[8 + jj][lane * 8]);
            float so = 0.f, si = 0.f;
#pragma unroll
            for (int e = 0; e < 8; ++e) {
                float kf = b2f((unsigned short)kv[u][e]);
                so += kf * b2f((unsigned short)qi[e]);
                si += kf * b2f((unsigned short)qj[e]);
            }
#pragma unroll
            for (int off = 1; off < 8; off <<= 1) {
                so += __shfl_xor(so, off);
                si += __shfl_xor(si, off);
            }
            if ((lane & 7) == 0) {
                souts[ii][jj][lane >> 3] = so * 0.125f;
                sins[jj][ii][lane >> 3]  = si * 0.125f;
            }
        }
    }
    __syncthreads();

    {
        int h  = t >> 5;
        int ii = (t >> 2) & 7;
        int qq = t & 3;
        f32x4 v;
#pragma unroll
        for (int e = 0; e < 4; ++e) v[e] = souts[ii][qq * 4 + e][h];
        *reinterpret_cast<f32x4*>(
            &outS[(((long long)(b * 8 + h) * 64) + i0 + ii) * 64 + j0 + qq * 4]) = v;
    }
    {
        int h  = t >> 5;
        int jj = (t >> 1) & 15;
        int hf = t & 1;
        f32x4 v;
#pragma unroll
        for (int e = 0; e < 4; ++e) v[e] = sins[jj][hf * 4 + e][h];
        *reinterpret_cast<f32x4*>(
            &inS[(((long long)(b * 8 + h) * 64) + j0 + jj) * 64 + i0 + hf * 4]) = v;
    }
}

// ---------------------------------------------------------------------------
__global__ __launch_bounds__(256)
void softmax_combine(float* __restrict__ outS, const float* __restrict__ inS)
{
    const long long row = (long long)blockIdx.x * 4 + (threadIdx.x >> 6);
    const int l = threadIdx.x & 63;
    const int x = (int)(row & 63);
    float so = outS[row * 64 + l];
    float si = inS[row * 64 + l];
    float mo = so, mi = si;
    for (int off = 32; off; off >>= 1) {
        mo = fmaxf(mo, __shfl_xor(mo, off));
        mi = fmaxf(mi, __shfl_xor(mi, off));
    }
    float eo = __expf(so - mo), ei = __expf(si - mi);
    float zo = eo, zi = ei;
    for (int off = 32; off; off >>= 1) {
        zo += __shfl_xor(zo, off);
        zi += __shfl_xor(zi, off);
    }
    float ao = eo / zo, ai = ei / zi;
    outS[row * 64 + l] = (l == x) ? ai : (ao + ai);
}

// ---------------------------------------------------------------------------
__global__ __launch_bounds__(512)
void nh_kernel(const float* __restrict__ msg,
               const unsigned short* __restrict__ v,
               unsigned short* __restrict__ nh)
{
    const int bm = blockIdx.x;
    const int b = bm >> 6, m = bm & 63;
    const int t = threadIdx.x;
    __shared__ float ms2[8 * 64];
    ms2[t] = msg[((long long)b * 8 + (t >> 6)) * 4096 + m * 64 + (t & 63)];
    __syncthreads();
    const float* mrow = &ms2[(t >> 6) * 64];
    float acc = 0.f;
#pragma unroll 8
    for (int n = 0; n < 64; ++n)
        acc += mrow[n] * b2f(v[((long long)b * 64 + n) * 512 + t]);
    nh[(long long)bm * 1024 + t] = f2b(acc);
}

// ---------------------------------------------------------------------------
extern "C" void kernel_launch(void* const* d_in, const int* in_sizes, int n_in,
                              void* d_out, int out_size, void* d_ws, size_t ws_size,
                              hipStream_t stream)
{
    const void* qn = d_in[0];
    const void* vn = d_in[1];
    const void* ke = d_in[2];
    const unsigned* adj = (const unsigned*)d_in[3];
    const void* Wq = d_in[4];  const void* bq = d_in[5];
    const void* Wk = d_in[6];  const void* bk = d_in[7];
    const void* Wv = d_in[8];  const void* bv = d_in[9];
    const void* Wn = d_in[10]; const void* bn = d_in[11];
    const void* We = d_in[12]; const void* be = d_in[13];

    float* out_node = (float*)d_out;                       // 16*64*512 f32 (2 MB)
    float* out_edge = out_node + (size_t)NB * NN * ND;     // 16*64*64*512 f32
    unsigned short* kp = (unsigned short*)out_edge;        // bf16, pitch 1024 shorts
    unsigned short* nh = (unsigned short*)out_node;        // bf16, pitch 1024 shorts
    float* inS = out_node;  // in-scores scratch (2 MB) — dead before nh_kernel

    char* wsb = (char*)d_ws;
    int* flag = (int*)wsb;
    unsigned short* Wt  = (unsigned short*)(wsb + 16);     // 5 x 512 KB
    unsigned short* Wqt = Wt + 0 * 262144;
    unsigned short* Wkt = Wt + 1 * 262144;
    unsigned short* Wvt = Wt + 2 * 262144;
    unsigned short* Wnt = Wt + 3 * 262144;
    unsigned short* Wet = Wt + 4 * 262144;
    unsigned short* q_ws = Wt + 5 * 262144;                // 1 MB bf16
    unsigned short* v_ws = q_ws + 524288;                  // 1 MB bf16
    float* msg = (float*)(v_ws + 524288);                  // 2 MB f32
    // ws total ~6.5 MB

    probe_dtype<<<1, 64, 0, stream>>>(adj, flag);
    wtrans<<<dim3(8, 8, 5), 256, 0, stream>>>(Wq, Wk, Wv, Wn, We, Wt, flag);
    // q + v projections merged (f32 A): blocks 0-15 -> q, 16-31 -> v
    gemm7<0, false, false><<<32, 256, 0, stream>>>(
        qn, 512, Wqt, bq, nullptr, q_ws, 512, flag, vn, Wvt, bv, v_ws);
    // k projection -> strided bf16 inside the edge f32 output region
    gemm7<0, false, false><<<1024, 256, 0, stream>>>(
        ke, 512, Wkt, bk, nullptr, kp, 1024, flag, nullptr, nullptr, nullptr, nullptr);
    // message: raw scores (kp read once) + softmax/combine
    score_kernel<<<512, 256, 0, stream>>>(q_ws, kp, msg, inS);
    softmax_combine<<<2048, 256, 0, stream>>>(msg, inS);
    // node path
    nh_kernel<<<NB * NN, 512, 0, stream>>>(msg, v_ws, nh);
    gemm7<1, true, true><<<16, 256, 0, stream>>>(
        nh, 1024, Wnt, bn, nullptr, out_node, 512, flag, nullptr, nullptr, nullptr, nullptr);
    // edge path: msg-scaling fused into A-staging; in-place
    gemm7<2, true, true><<<1024, 256, 0, stream>>>(
        kp, 1024, Wet, be, msg, out_edge, 512, flag, nullptr, nullptr, nullptr, nullptr);
}